// Round 10
// baseline (1590.870 us; speedup 1.0000x reference)
//
#include <hip/hip_runtime.h>

// Problem constants: V=27, E=64, H=128, B=256, S=512 (enc and dec)
#define V_ 27
#define E_ 64
#define H_ 128
#define S_ 512

typedef float f32x2 __attribute__((ext_vector_type(2)));
typedef float f32x4 __attribute__((ext_vector_type(4)));

// Hazard-safe DPP add (compiler inserts required wait states).
template<int CTRL>
__device__ __forceinline__ float dpp_add(float x) {
    int y = __builtin_amdgcn_update_dpp(0, __builtin_bit_cast(int, x), CTRL, 0xF, 0xF, true);
    return x + __builtin_bit_cast(float, y);
}
#define QP_1032 0xB1   // quad_perm [1,0,3,2]: pair-swap lanes

// tanh(z) = 1 - 2/(e^{2z}+1); fp32-stable at both extremes.
__device__ __forceinline__ float fast_tanhf(float z) {
    float e = __expf(2.0f * z);
    return 1.0f - __fdividef(2.0f, e + 1.0f);
}

// ---------------- X-macro lists ----------------
#define WQ64(X) X(0) X(1) X(2) X(3) X(4) X(5) X(6) X(7) X(8) X(9) \
 X(10) X(11) X(12) X(13) X(14) X(15) X(16) X(17) X(18) X(19) \
 X(20) X(21) X(22) X(23) X(24) X(25) X(26) X(27) X(28) X(29) \
 X(30) X(31) X(32) X(33) X(34) X(35) X(36) X(37) X(38) X(39) \
 X(40) X(41) X(42) X(43) X(44) X(45) X(46) X(47) X(48) X(49) \
 X(50) X(51) X(52) X(53) X(54) X(55) X(56) X(57) X(58) X(59) \
 X(60) X(61) X(62) X(63)
#define WQ32(X) X(0) X(1) X(2) X(3) X(4) X(5) X(6) X(7) X(8) X(9) \
 X(10) X(11) X(12) X(13) X(14) X(15) X(16) X(17) X(18) X(19) \
 X(20) X(21) X(22) X(23) X(24) X(25) X(26) X(27) X(28) X(29) \
 X(30) X(31)
#define DQ16(X) X(0) X(1) X(2) X(3) X(4) X(5) X(6) X(7) X(8) X(9) \
 X(10) X(11) X(12) X(13) X(14) X(15)

#define DECLQ(n) f32x4 wq##n;
#define DECLD(n) f32x4 dq##n;
// wq_n = (Wh[2n][j0], Wh[2n][j1], Wh[2n+1][j0], Wh[2n+1][j1]), j0=2*lane, j1=j0+1
#define LW(n) { wq##n.xy = *(const f32x2*)(wbase + (2*(n))*H_ + loff); \
                wq##n.zw = *(const f32x2*)(wbase + (2*(n)+1)*H_ + loff); }
// dq_n = dense_W[64*half + 4n .. +3][vc]
#define LD(n) { dq##n.x = dbase[(4*(n)+0)*V_]; dq##n.y = dbase[(4*(n)+1)*V_]; \
                dq##n.z = dbase[(4*(n)+2)*V_]; dq##n.w = dbase[(4*(n)+3)*V_]; }

// 4 k-rows of recurrence FMA: PE/PO are f32x2 accumulators (j0,j1)
#define RC2(HC, WA, WB, PE, PO) { \
    f32x2 _h0 = {(HC).x, (HC).x}; PE = __builtin_elementwise_fma(_h0, (WA).xy, PE); \
    f32x2 _h1 = {(HC).y, (HC).y}; PO = __builtin_elementwise_fma(_h1, (WA).zw, PO); \
    f32x2 _h2 = {(HC).z, (HC).z}; PE = __builtin_elementwise_fma(_h2, (WB).xy, PE); \
    f32x2 _h3 = {(HC).w, (HC).w}; PO = __builtin_elementwise_fma(_h3, (WB).zw, PO); }

#define DC(HC, DQ, DA) { \
    DA = __builtin_elementwise_fma((HC).xy, (DQ).xy, DA); \
    DA = __builtin_elementwise_fma((HC).zw, (DQ).zw, DA); }

#define CHUNK(c, WA, WB, PE, PO, DQ, DA, DENSEF) { \
    f32x4 _hc = hb[c]; RC2(_hc, WA, WB, PE, PO); if (DENSEF) DC(_hc, DQ, DA); }

#define PCHUNK(c, WA, WB, PE, PO) { f32x4 _ec = ebp[c]; RC2(_ec, WA, WB, PE, PO); }

// One RNN step, single wave, NO barrier. h broadcast-read from LDS (32 uniform
// b128), h written as one b64/lane. DS pipe is in-order within a wave -> the
// next step's reads see this step's write without any sync.
#define RNN_STEP(HSRC, HDST, DENSEF, LOADPAIRF, IDP, TOFF, DOSTORE, OUTP) do {   \
    int2 idpr_n = idpr;                                                          \
    if (LOADPAIRF) idpr_n = *(const int2*)((IDP) + 2);   /* ids t+2,t+3 */       \
    f32x2 Tv_n = *(const f32x2*)(lds_T + (TOFF) + id_next * H_ + loff);          \
    const f32x4* hb = (const f32x4*)(HSRC);                                      \
    f32x2 pa={0.f,0.f}, pb={0.f,0.f}, pc={0.f,0.f}, pd={0.f,0.f};                \
    f32x2 d2a={0.f,0.f}, d2b={0.f,0.f};                                          \
    CHUNK( 0, wq0,  wq1,  pa, pb, dq0,  d2a, DENSEF);                            \
    CHUNK( 1, wq2,  wq3,  pc, pd, dq1,  d2a, DENSEF);                            \
    CHUNK( 2, wq4,  wq5,  pa, pb, dq2,  d2a, DENSEF);                            \
    CHUNK( 3, wq6,  wq7,  pc, pd, dq3,  d2a, DENSEF);                            \
    CHUNK( 4, wq8,  wq9,  pa, pb, dq4,  d2a, DENSEF);                            \
    CHUNK( 5, wq10, wq11, pc, pd, dq5,  d2a, DENSEF);                            \
    CHUNK( 6, wq12, wq13, pa, pb, dq6,  d2a, DENSEF);                            \
    CHUNK( 7, wq14, wq15, pc, pd, dq7,  d2a, DENSEF);                            \
    CHUNK( 8, wq16, wq17, pa, pb, dq8,  d2a, DENSEF);                            \
    CHUNK( 9, wq18, wq19, pc, pd, dq9,  d2a, DENSEF);                            \
    CHUNK(10, wq20, wq21, pa, pb, dq10, d2a, DENSEF);                            \
    CHUNK(11, wq22, wq23, pc, pd, dq11, d2a, DENSEF);                            \
    CHUNK(12, wq24, wq25, pa, pb, dq12, d2a, DENSEF);                            \
    CHUNK(13, wq26, wq27, pc, pd, dq13, d2a, DENSEF);                            \
    CHUNK(14, wq28, wq29, pa, pb, dq14, d2a, DENSEF);                            \
    CHUNK(15, wq30, wq31, pc, pd, dq15, d2a, DENSEF);                            \
    CHUNK(16, wq32, wq33, pa, pb, dq0,  d2b, DENSEF);                            \
    CHUNK(17, wq34, wq35, pc, pd, dq1,  d2b, DENSEF);                            \
    CHUNK(18, wq36, wq37, pa, pb, dq2,  d2b, DENSEF);                            \
    CHUNK(19, wq38, wq39, pc, pd, dq3,  d2b, DENSEF);                            \
    CHUNK(20, wq40, wq41, pa, pb, dq4,  d2b, DENSEF);                            \
    CHUNK(21, wq42, wq43, pc, pd, dq5,  d2b, DENSEF);                            \
    CHUNK(22, wq44, wq45, pa, pb, dq6,  d2b, DENSEF);                            \
    CHUNK(23, wq46, wq47, pc, pd, dq7,  d2b, DENSEF);                            \
    CHUNK(24, wq48, wq49, pa, pb, dq8,  d2b, DENSEF);                            \
    CHUNK(25, wq50, wq51, pc, pd, dq9,  d2b, DENSEF);                            \
    CHUNK(26, wq52, wq53, pa, pb, dq10, d2b, DENSEF);                            \
    CHUNK(27, wq54, wq55, pc, pd, dq11, d2b, DENSEF);                            \
    CHUNK(28, wq56, wq57, pa, pb, dq12, d2b, DENSEF);                            \
    CHUNK(29, wq58, wq59, pc, pd, dq13, d2b, DENSEF);                            \
    CHUNK(30, wq60, wq61, pa, pb, dq14, d2b, DENSEF);                            \
    CHUNK(31, wq62, wq63, pc, pd, dq15, d2b, DENSEF);                            \
    f32x2 p = (pa + pb) + (pc + pd);                                             \
    p = p + Tv;                                                                  \
    f32x2 hn; hn.x = fast_tanhf(p.x); hn.y = fast_tanhf(p.y);                    \
    *(f32x2*)((HDST) + loff) = hn;                       /* ds_write_b64 */      \
    if (DENSEF) {                                                                \
        f32x2 dsel = half ? d2b : d2a;   /* lane's dq matches its k-half */      \
        float d = dsel.x + dsel.y;                                               \
        d = dpp_add<QP_1032>(d);         /* pair lanes: low-k + high-k */        \
        if (DOSTORE) (OUTP)[0] = d + db;                                         \
    }                                                                            \
    if (LOADPAIRF) { idpr = idpr_n; id_next = idpr_n.x; }                        \
    else           { id_next = idpr.y; }                                         \
    Tv = Tv_n;                                                                   \
} while (0)

// Dense-only chunk for the epilogue
#define EC(n) { f32x4 _ha = hb[n]; DC(_ha, dq##n, d2a); \
                f32x4 _hb2 = hb[(n)+16]; DC(_hb2, dq##n, d2b); }

// One wave per batch row: 256 blocks x 64 threads, no __syncthreads anywhere.
__global__ __attribute__((amdgpu_flat_work_group_size(64, 64), amdgpu_waves_per_eu(1, 1)))
void seq2seq_rnn_kernel(const int* __restrict__ enc_ids, const int* __restrict__ dec_ids,
                        const float* __restrict__ embed,
                        const float* __restrict__ enc_Wx, const float* __restrict__ enc_Wh,
                        const float* __restrict__ enc_b,
                        const float* __restrict__ dec_Wx, const float* __restrict__ dec_Wh,
                        const float* __restrict__ dec_b,
                        const float* __restrict__ dense_W, const float* __restrict__ dense_b,
                        float* __restrict__ out) {
    __shared__ __align__(16) float lds_T[2 * V_ * H_];   // xw tables [tbl][v][j]
    __shared__ __align__(16) float lds_emb[V_ * E_];
    __shared__ __align__(16) float lds_h0[H_];
    __shared__ __align__(16) float lds_h1[H_];
    __shared__ __align__(16) int   lds_ids[2 * S_ + 2];

    const int lane = threadIdx.x;        // 0..63
    const int b    = blockIdx.x;
    const int loff = lane << 1;          // word offset of owned pair (j0,j1)
    const int half = lane & 1;           // dense k-half
    const int vc   = ((lane >> 1) < V_) ? (lane >> 1) : (V_ - 1);
    const bool dlane = ((lane & 1) == 0) && ((lane >> 1) < V_);

    // ---- stage embed + ids; zero h0 (all single-wave, in-order DS) ----
    for (int i = lane; i < (V_ * E_) / 4; i += 64)
        ((f32x4*)lds_emb)[i] = ((const f32x4*)embed)[i];
    ((int4*)lds_ids)[lane]      = ((const int4*)(enc_ids + b * S_))[lane];
    ((int4*)lds_ids)[lane + 64] = ((const int4*)(enc_ids + b * S_))[lane + 64];
    ((int4*)(lds_ids + S_))[lane]      = ((const int4*)(dec_ids + b * S_))[lane];
    ((int4*)(lds_ids + S_))[lane + 64] = ((const int4*)(dec_ids + b * S_))[lane + 64];
    if (lane < 2) lds_ids[2 * S_ + lane] = 0;
    { f32x2 z2; z2.x = 0.f; z2.y = 0.f; *(f32x2*)(lds_h0 + loff) = z2; }

    // ---- declare weight registers ----
    WQ64(DECLQ)         // wq0..wq63: 256 VGPRs of Wh columns (j0,j1)
    DQ16(DECLD)         // dq0..dq15: 64 VGPRs of dense column (lane's k-half)

    // ---- T tables: T[tbl][v][j0,j1] = b + sum_e emb[v][e] * Wx[e][j0,j1] ----
    for (int tbl = 0; tbl < 2; ++tbl) {
        const float* wxsrc = tbl ? dec_Wx : enc_Wx;
        { const float* wbase = wxsrc; WQ32(LW) }     // Wx rows into wq0..31
        const float* bbp = tbl ? dec_b : enc_b;
        f32x2 bia = *(const f32x2*)(bbp + loff);
        float* tdst = lds_T + tbl * (V_ * H_);
        #pragma unroll 1
        for (int v = 0; v < V_; ++v) {
            const f32x4* ebp = (const f32x4*)(lds_emb + v * E_);
            f32x2 qa={0.f,0.f}, qb={0.f,0.f}, qc={0.f,0.f}, qd={0.f,0.f};
            PCHUNK( 0, wq0,  wq1,  qa, qb); PCHUNK( 1, wq2,  wq3,  qc, qd);
            PCHUNK( 2, wq4,  wq5,  qa, qb); PCHUNK( 3, wq6,  wq7,  qc, qd);
            PCHUNK( 4, wq8,  wq9,  qa, qb); PCHUNK( 5, wq10, wq11, qc, qd);
            PCHUNK( 6, wq12, wq13, qa, qb); PCHUNK( 7, wq14, wq15, qc, qd);
            PCHUNK( 8, wq16, wq17, qa, qb); PCHUNK( 9, wq18, wq19, qc, qd);
            PCHUNK(10, wq20, wq21, qa, qb); PCHUNK(11, wq22, wq23, qc, qd);
            PCHUNK(12, wq24, wq25, qa, qb); PCHUNK(13, wq26, wq27, qc, qd);
            PCHUNK(14, wq28, wq29, qa, qb); PCHUNK(15, wq30, wq31, qc, qd);
            f32x2 q = ((qa + qb) + (qc + qd)) + bia;
            *(f32x2*)(tdst + v * H_ + loff) = q;
        }
    }

    // ---- dense weights (lane's k-half of its v column) ----
    { const float* dbase = dense_W + (64 * half) * V_ + vc; DQ16(LD) }
    const float db = dense_b[vc];
    float* outd = out + b * (S_ * V_) + (lane >> 1);

    // ---- encoder recurrent weights into wq0..63 ----
    { const float* wbase = enc_Wh; WQ64(LW) }

    // ================= encoder: 512 steps, no barriers =================
    {
        const int* ids_p = lds_ids;
        int2 idpr; idpr.x = 0; idpr.y = 0;
        int id_next = ids_p[1];
        f32x2 Tv = *(const f32x2*)(lds_T + ids_p[0] * H_ + loff);
        #pragma unroll 1
        for (int t = 0; t < S_; t += 2) {
            RNN_STEP(lds_h0, lds_h1, false, true,  ids_p + t, 0, false, outd);
            RNN_STEP(lds_h1, lds_h0, false, false, ids_p + t, 0, false, outd);
        }
    }

    // ---- swap to decoder recurrent weights ----
    { const float* wbase = dec_Wh; WQ64(LW) }

    // ================= decoder: 512 steps; dense piggybacked =================
    // Step t reads state after step t-1 -> dense on it -> out[(t-1)*V].
    {
        const int* ids_p = lds_ids + S_;
        int2 idpr; idpr.x = 0; idpr.y = 0;
        int id_next = ids_p[1];
        f32x2 Tv = *(const f32x2*)(lds_T + V_ * H_ + ids_p[0] * H_ + loff);
        #pragma unroll 1
        for (int t = 0; t < S_; t += 2) {
            RNN_STEP(lds_h0, lds_h1, true, true,  ids_p + t, V_ * H_,
                     dlane && (t > 0), outd + (t - 1) * V_);
            RNN_STEP(lds_h1, lds_h0, true, false, ids_p + t, V_ * H_,
                     dlane, outd + t * V_);
        }
    }

    // epilogue: dense on final state (decoder ended writing lds_h0) -> logits[511]
    {
        const f32x4* hb = (const f32x4*)lds_h0;
        f32x2 d2a={0.f,0.f}, d2b={0.f,0.f};
        DQ16(EC)
        f32x2 dsel = half ? d2b : d2a;
        float d = dsel.x + dsel.y;
        d = dpp_add<QP_1032>(d);
        if (dlane) outd[(S_ - 1) * V_] = d + db;
    }
}

extern "C" void kernel_launch(void* const* d_in, const int* in_sizes, int n_in,
                              void* d_out, int out_size, void* d_ws, size_t ws_size,
                              hipStream_t stream) {
    const int*   enc_ids = (const int*)d_in[0];
    const int*   dec_ids = (const int*)d_in[1];
    const float* embed   = (const float*)d_in[2];
    const float* enc_Wx  = (const float*)d_in[3];
    const float* enc_Wh  = (const float*)d_in[4];
    const float* enc_b   = (const float*)d_in[5];
    const float* dec_Wx  = (const float*)d_in[6];
    const float* dec_Wh  = (const float*)d_in[7];
    const float* dec_b   = (const float*)d_in[8];
    const float* dense_W = (const float*)d_in[9];
    const float* dense_b = (const float*)d_in[10];
    float* out = (float*)d_out;

    hipLaunchKernelGGL(seq2seq_rnn_kernel, dim3(256), dim3(64), 0, stream,
                       enc_ids, dec_ids, embed, enc_Wx, enc_Wh, enc_b,
                       dec_Wx, dec_Wh, dec_b, dense_W, dense_b, out);
}

// Round 11
// 444.979 us; speedup vs baseline: 3.5752x; 3.5752x over previous
//
#include <hip/hip_runtime.h>

// Problem constants: V=27, E=64, H=128, B=256, S=512 (enc and dec)
#define V_ 27
#define E_ 64
#define H_ 128
#define S_ 512

typedef float f32x2 __attribute__((ext_vector_type(2)));
typedef float f32x4 __attribute__((ext_vector_type(4)));

// Barrier WITHOUT vmcnt drain: LDS visibility only. Global loads/stores stay in flight.
#define BAR() asm volatile("s_waitcnt lgkmcnt(0)\n\ts_barrier" ::: "memory")

// Per-iteration pins: keep weight registers resident (defeat remat; R7/R8 lesson).
#define PINW() do { \
    asm volatile("" : "+v"(wk0a), "+v"(wk0b), "+v"(wk1a), "+v"(wk1b), \
                      "+v"(wk2a), "+v"(wk2b), "+v"(wk3a), "+v"(wk3b)); \
    asm volatile("" : "+v"(wk4a), "+v"(wk4b), "+v"(wk5a), "+v"(wk5b), \
                      "+v"(wk6a), "+v"(wk6b), "+v"(wk7a), "+v"(wk7b)); \
} while (0)
#define PIND() asm volatile("" : "+v"(DA0), "+v"(DA1), "+v"(DB0), "+v"(DB1))

// Hazard-safe DPP add (compiler inserts required wait states).
template<int CTRL>
__device__ __forceinline__ float dpp_add(float x) {
    int y = __builtin_amdgcn_update_dpp(0, __builtin_bit_cast(int, x), CTRL, 0xF, 0xF, true);
    return x + __builtin_bit_cast(float, y);
}
#define QP_1032 0xB1   // quad_perm [1,0,3,2]
#define QP_2301 0x4E   // quad_perm [2,3,0,1]
#define RR8 0x128      // row_ror:8
#define RR4 0x124      // row_ror:4
#define RR2 0x122      // row_ror:2
#define RR1 0x121      // row_ror:1

// tanh(z) = 1 - 2/(e^{2z}+1); fp32-stable at both extremes.
__device__ __forceinline__ float fast_tanhf(float z) {
    float e = __expf(2.0f * z);
    return 1.0f - __fdividef(2.0f, e + 1.0f);
}

// ---------- prep kernel: T[tbl][v][j] = b[j] + sum_e embed[v][e]*Wx[e][j] ----------
__global__ void prep_T(const float* __restrict__ embed,
                       const float* __restrict__ eWx, const float* __restrict__ eb,
                       const float* __restrict__ dWx, const float* __restrict__ db_,
                       float* __restrict__ Tg) {
    int tbl = blockIdx.x / V_;
    int v   = blockIdx.x - tbl * V_;
    int j   = threadIdx.x;
    const float* Wx = tbl ? dWx : eWx;
    const float* bb = tbl ? db_ : eb;
    float s = bb[j];
    #pragma unroll
    for (int e = 0; e < E_; ++e) s = fmaf(embed[v * E_ + e], Wx[e * H_ + j], s);
    Tg[tbl * V_ * H_ + v * H_ + j] = s;
}

// One k-row of recurrence: accumulate h[k] against 8 j's (4 packed f32x2 accs).
#define KROW(HV, WA, WB) do { \
    f32x2 _h2 = {(HV), (HV)}; \
    A0 = __builtin_elementwise_fma(_h2, (WA).xy, A0); \
    A1 = __builtin_elementwise_fma(_h2, (WA).zw, A1); \
    A2 = __builtin_elementwise_fma(_h2, (WB).xy, A2); \
    A3 = __builtin_elementwise_fma(_h2, (WB).zw, A3); \
} while (0)

// ---------- main kernel: 256 blocks x 256 threads (4 waves = 1 wave/SIMD) ----------
// Wave w owns j in [32w, 32w+32). lane = (jl<<4)|kk:
//   jl = lane>>4 (0..3): j-group of 8, j0 = 32w + 8jl
//   kk = lane&15: 8 k's [8kk, 8kk+8)
// Per lane/step: 2 ds_read_b128 (hv), 32 pk-FMA, quad-DPP reduce (16), diagonal
// select (6 cndmask) -> lane owns j-pair jsel = j0+2*(kk&3), ror8+ror4 (4 DPP),
// 2 tanh, kk<4 lanes ds_write_b64. Tv from GLOBAL T (prefetched 1 step ahead;
// BAR never drains vmcnt). Dense: group (w,jl) covers logits va=(w<<2)|jl and
// vb=va+16 reusing hv; full 16-lane ror reduce; kk==0 stores.
#define RNN_STEP(HSRC, HDST, DENSEF, LOADPAIRF, IDP, TGB, DOSTORE, OUTP) do {       \
    PINW();                                                                         \
    if (DENSEF) PIND();                                                             \
    int2 idpr_n = idpr;                                                             \
    if (LOADPAIRF) idpr_n = *(const int2*)((IDP) + 2);    /* ids t+2,t+3 (b64) */   \
    f32x2 Tv_n = *(const f32x2*)((TGB) + id_next * H_ + jsel);                      \
    const f32x4* hbp = (const f32x4*)((HSRC) + 8 * kk);                             \
    f32x4 ha = hbp[0], hc = hbp[1];                       /* 2x ds_read_b128 */     \
    f32x2 A0 = {0.f,0.f}, A1 = {0.f,0.f}, A2 = {0.f,0.f}, A3 = {0.f,0.f};           \
    KROW(ha.x, wk0a, wk0b); KROW(ha.y, wk1a, wk1b);                                 \
    KROW(ha.z, wk2a, wk2b); KROW(ha.w, wk3a, wk3b);                                 \
    KROW(hc.x, wk4a, wk4b); KROW(hc.y, wk5a, wk5b);                                 \
    KROW(hc.z, wk6a, wk6b); KROW(hc.w, wk7a, wk7b);                                 \
    float s0 = A0.x, s1 = A0.y, s2 = A1.x, s3 = A1.y;                               \
    float s4 = A2.x, s5 = A2.y, s6 = A3.x, s7 = A3.y;                               \
    s0 = dpp_add<QP_2301>(dpp_add<QP_1032>(s0));                                    \
    s1 = dpp_add<QP_2301>(dpp_add<QP_1032>(s1));                                    \
    s2 = dpp_add<QP_2301>(dpp_add<QP_1032>(s2));                                    \
    s3 = dpp_add<QP_2301>(dpp_add<QP_1032>(s3));                                    \
    s4 = dpp_add<QP_2301>(dpp_add<QP_1032>(s4));                                    \
    s5 = dpp_add<QP_2301>(dpp_add<QP_1032>(s5));                                    \
    s6 = dpp_add<QP_2301>(dpp_add<QP_1032>(s6));                                    \
    s7 = dpp_add<QP_2301>(dpp_add<QP_1032>(s7));                                    \
    float r0 = c1 ? s2 : s0;  float r0b = c1 ? s6 : s4;  r0 = c2 ? r0b : r0;        \
    float r1 = c1 ? s3 : s1;  float r1b = c1 ? s7 : s5;  r1 = c2 ? r1b : r1;        \
    r0 = dpp_add<RR4>(dpp_add<RR8>(r0));                                            \
    r1 = dpp_add<RR4>(dpp_add<RR8>(r1));                                            \
    f32x2 hn; hn.x = fast_tanhf(r0 + Tv.x); hn.y = fast_tanhf(r1 + Tv.y);           \
    if (wrlane) *(f32x2*)((HDST) + jsel) = hn;            /* b64, 4 lanes/wave */   \
    if (DENSEF) {                                                                   \
        f32x2 d2a = ha.xy * DA0.xy;                                                 \
        d2a = __builtin_elementwise_fma(ha.zw, DA0.zw, d2a);                        \
        d2a = __builtin_elementwise_fma(hc.xy, DA1.xy, d2a);                        \
        d2a = __builtin_elementwise_fma(hc.zw, DA1.zw, d2a);                        \
        f32x2 d2b = ha.xy * DB0.xy;                                                 \
        d2b = __builtin_elementwise_fma(ha.zw, DB0.zw, d2b);                        \
        d2b = __builtin_elementwise_fma(hc.xy, DB1.xy, d2b);                        \
        d2b = __builtin_elementwise_fma(hc.zw, DB1.zw, d2b);                        \
        float da = d2a.x + d2a.y;                                                   \
        float dv = d2b.x + d2b.y;                                                   \
        da = dpp_add<RR1>(dpp_add<RR2>(dpp_add<RR4>(dpp_add<RR8>(da))));            \
        dv = dpp_add<RR1>(dpp_add<RR2>(dpp_add<RR4>(dpp_add<RR8>(dv))));            \
        if (DOSTORE) {                                                              \
            (OUTP)[va] = da + dba;                        /* vmcnt never drained */ \
            if (vb < V_) (OUTP)[vb] = dv + dbb;                                     \
        }                                                                           \
    }                                                                               \
    BAR();                                                                          \
    if (LOADPAIRF) { idpr = idpr_n; id_next = idpr_n.x; }                           \
    else           { id_next = idpr.y; }                                            \
    Tv = Tv_n;                                                                      \
} while (0)

__global__ __attribute__((amdgpu_flat_work_group_size(256, 256), amdgpu_waves_per_eu(1, 1)))
void seq2seq_rnn_kernel(const int* __restrict__ enc_ids, const int* __restrict__ dec_ids,
                        const float* __restrict__ enc_Wh, const float* __restrict__ dec_Wh,
                        const float* __restrict__ dense_W, const float* __restrict__ dense_b,
                        const float* __restrict__ Tg,      // [2][27][128] in d_ws
                        float* __restrict__ out) {
    __shared__ __align__(16) float lds_h0[H_];
    __shared__ __align__(16) float lds_h1[H_];
    __shared__ __align__(16) int   lds_ids[2 * S_ + 2];

    const int tid  = threadIdx.x;
    const int b    = blockIdx.x;
    const int lane = tid & 63;
    const int w    = tid >> 6;            // wave 0..3
    const int jl   = lane >> 4;           // 0..3
    const int kk   = lane & 15;
    const int j0   = (w << 5) + (jl << 3);     // first of 8 owned j
    const int jsel = j0 + 2 * (kk & 3);        // lane's final j-pair
    const bool wrlane = (kk < 4);
    const bool c1 = (kk & 1) != 0;
    const bool c2 = (kk & 2) != 0;
    const int va = (w << 2) | jl;              // dense logit A (0..15)
    const int vb = va + 16;                    // dense logit B (16..31, 27 used)

    // ---- stage ids; zero h0 ----
    if (tid < 128) ((int4*)lds_ids)[tid] = ((const int4*)(enc_ids + b * S_))[tid];
    else           ((int4*)lds_ids)[tid] = ((const int4*)(dec_ids + b * S_))[tid - 128];
    if (tid < 2) lds_ids[2 * S_ + tid] = 0;
    if (tid < 64) { f32x2 z2; z2.x = 0.f; z2.y = 0.f; *(f32x2*)(lds_h0 + 2 * tid) = z2; }

    // ---- recurrent weights: wk{i}{a,b} = Wh[(8kk+i)*H + j0 .. j0+7] (two b128) ----
    f32x4 wk0a, wk0b, wk1a, wk1b, wk2a, wk2b, wk3a, wk3b;
    f32x4 wk4a, wk4b, wk5a, wk5b, wk6a, wk6b, wk7a, wk7b;
#define LOADW(SRC) do { \
    const float* wp = (SRC) + (8 * kk) * H_ + j0; \
    wk0a = *(const f32x4*)(wp + 0 * H_);     wk0b = *(const f32x4*)(wp + 0 * H_ + 4); \
    wk1a = *(const f32x4*)(wp + 1 * H_);     wk1b = *(const f32x4*)(wp + 1 * H_ + 4); \
    wk2a = *(const f32x4*)(wp + 2 * H_);     wk2b = *(const f32x4*)(wp + 2 * H_ + 4); \
    wk3a = *(const f32x4*)(wp + 3 * H_);     wk3b = *(const f32x4*)(wp + 3 * H_ + 4); \
    wk4a = *(const f32x4*)(wp + 4 * H_);     wk4b = *(const f32x4*)(wp + 4 * H_ + 4); \
    wk5a = *(const f32x4*)(wp + 5 * H_);     wk5b = *(const f32x4*)(wp + 5 * H_ + 4); \
    wk6a = *(const f32x4*)(wp + 6 * H_);     wk6b = *(const f32x4*)(wp + 6 * H_ + 4); \
    wk7a = *(const f32x4*)(wp + 7 * H_);     wk7b = *(const f32x4*)(wp + 7 * H_ + 4); \
} while (0)
    LOADW(enc_Wh);

    // ---- dense weights: DA = dense_W[8kk+i][va], DB = [vb] (i=0..7) ----
    f32x4 DA0, DA1, DB0, DB1;
    float dba, dbb;
    {
        int vbc = (vb < V_) ? vb : 0;
        const float* dpa = dense_W + (8 * kk) * V_ + va;
        const float* dpb = dense_W + (8 * kk) * V_ + vbc;
        DA0.x = dpa[0 * V_]; DA0.y = dpa[1 * V_]; DA0.z = dpa[2 * V_]; DA0.w = dpa[3 * V_];
        DA1.x = dpa[4 * V_]; DA1.y = dpa[5 * V_]; DA1.z = dpa[6 * V_]; DA1.w = dpa[7 * V_];
        DB0.x = dpb[0 * V_]; DB0.y = dpb[1 * V_]; DB0.z = dpb[2 * V_]; DB0.w = dpb[3 * V_];
        DB1.x = dpb[4 * V_]; DB1.y = dpb[5 * V_]; DB1.z = dpb[6 * V_]; DB1.w = dpb[7 * V_];
        dba = dense_b[va];
        dbb = dense_b[vbc];
    }
    const bool dlane = (kk == 0);
    float* outb = out + b * (S_ * V_);
    __syncthreads();   // ids + h0 ready

    // ================= encoder: 512 steps =================
    {
        int2  idpr; idpr.x = 0; idpr.y = 0;
        int   id_next = lds_ids[1];
        f32x2 Tv = *(const f32x2*)(Tg + lds_ids[0] * H_ + jsel);
        #pragma unroll 1
        for (int t = 0; t < S_; t += 2) {
            RNN_STEP(lds_h0, lds_h1, false, true,  lds_ids + t, Tg, false, outb);
            RNN_STEP(lds_h1, lds_h0, false, false, lds_ids + t, Tg, false, outb);
        }
    }

    // ---- swap to decoder recurrent weights (registers private; BAR above synced) ----
    LOADW(dec_Wh);

    // ================= decoder: 512 steps; dense piggybacked =================
    // Step t reads state after step t-1 -> dense on it -> out[(t-1)*V].
    {
        const int*   ids_d = lds_ids + S_;
        const float* Td    = Tg + V_ * H_;
        int2  idpr; idpr.x = 0; idpr.y = 0;
        int   id_next = ids_d[1];
        f32x2 Tv = *(const f32x2*)(Td + ids_d[0] * H_ + jsel);
        #pragma unroll 1
        for (int t = 0; t < S_; t += 2) {
            RNN_STEP(lds_h0, lds_h1, true, true,  ids_d + t, Td,
                     dlane && (t > 0), outb + (t - 1) * V_);
            RNN_STEP(lds_h1, lds_h0, true, false, ids_d + t, Td,
                     dlane, outb + t * V_);
        }
    }

    // epilogue: dense on final state (decoder ended writing lds_h0) -> logits[511]
    {
        const f32x4* hbp = (const f32x4*)(lds_h0 + 8 * kk);
        f32x4 ha = hbp[0], hc = hbp[1];
        f32x2 d2a = ha.xy * DA0.xy;
        d2a = __builtin_elementwise_fma(ha.zw, DA0.zw, d2a);
        d2a = __builtin_elementwise_fma(hc.xy, DA1.xy, d2a);
        d2a = __builtin_elementwise_fma(hc.zw, DA1.zw, d2a);
        f32x2 d2b = ha.xy * DB0.xy;
        d2b = __builtin_elementwise_fma(ha.zw, DB0.zw, d2b);
        d2b = __builtin_elementwise_fma(hc.xy, DB1.xy, d2b);
        d2b = __builtin_elementwise_fma(hc.zw, DB1.zw, d2b);
        float da = d2a.x + d2a.y;
        float dv = d2b.x + d2b.y;
        da = dpp_add<RR1>(dpp_add<RR2>(dpp_add<RR4>(dpp_add<RR8>(da))));
        dv = dpp_add<RR1>(dpp_add<RR2>(dpp_add<RR4>(dpp_add<RR8>(dv))));
        if (dlane) {
            float* op = outb + (S_ - 1) * V_;
            op[va] = da + dba;
            if (vb < V_) op[vb] = dv + dbb;
        }
    }
}

extern "C" void kernel_launch(void* const* d_in, const int* in_sizes, int n_in,
                              void* d_out, int out_size, void* d_ws, size_t ws_size,
                              hipStream_t stream) {
    const int*   enc_ids = (const int*)d_in[0];
    const int*   dec_ids = (const int*)d_in[1];
    const float* embed   = (const float*)d_in[2];
    const float* enc_Wx  = (const float*)d_in[3];
    const float* enc_Wh  = (const float*)d_in[4];
    const float* enc_b   = (const float*)d_in[5];
    const float* dec_Wx  = (const float*)d_in[6];
    const float* dec_Wh  = (const float*)d_in[7];
    const float* dec_b   = (const float*)d_in[8];
    const float* dense_W = (const float*)d_in[9];
    const float* dense_b = (const float*)d_in[10];
    float* out = (float*)d_out;
    float* Tg  = (float*)d_ws;   // 2*27*128 floats = 27648 B

    hipLaunchKernelGGL(prep_T, dim3(2 * V_), dim3(H_), 0, stream,
                       embed, enc_Wx, enc_b, dec_Wx, dec_b, Tg);
    hipLaunchKernelGGL(seq2seq_rnn_kernel, dim3(256), dim3(256), 0, stream,
                       enc_ids, dec_ids, enc_Wh, dec_Wh, dense_W, dense_b, Tg, out);
}

// Round 12
// 417.531 us; speedup vs baseline: 3.8102x; 1.0657x over previous
//
#include <hip/hip_runtime.h>

// Problem constants: V=27, E=64, H=128, B=256, S=512 (enc and dec)
#define V_ 27
#define E_ 64
#define H_ 128
#define S_ 512

typedef float f32x4 __attribute__((ext_vector_type(4)));
typedef float f32x2 __attribute__((ext_vector_type(2)));

// Barrier WITHOUT vmcnt drain: LDS visibility only. Global stores stay in flight.
#define BAR() asm volatile("s_waitcnt lgkmcnt(0)\n\ts_barrier" ::: "memory")

// Per-iteration register pins: force weight residency (defeat remat; R7/R8 lesson).
#define PINW() asm volatile("" : "+v"(R0), "+v"(R1), "+v"(R2), "+v"(R3), \
                                 "+v"(R4), "+v"(R5), "+v"(R6), "+v"(R7))
#define PIND() asm volatile("" : "+v"(D0), "+v"(D1))

// Hazard-safe DPP add (compiler inserts required wait states).
template<int CTRL>
__device__ __forceinline__ float dpp_add(float x) {
    int y = __builtin_amdgcn_update_dpp(0, __builtin_bit_cast(int, x), CTRL, 0xF, 0xF, true);
    return x + __builtin_bit_cast(float, y);
}
#define QP_1032 0xB1   // quad_perm [1,0,3,2]
#define QP_2301 0x4E   // quad_perm [2,3,0,1]
#define RR8 0x128      // row_ror:8
#define RR4 0x124      // row_ror:4
#define RR2 0x122      // row_ror:2
#define RR1 0x121      // row_ror:1

// tanh(z) = 1 - 2/(e^{2z}+1); fp32-stable at both extremes.
__device__ __forceinline__ float fast_tanhf(float z) {
    float e = __expf(2.0f * z);
    return 1.0f - __fdividef(2.0f, e + 1.0f);
}

// Packed dual-FMA accumulate (v_pk_fma_f32); summation order identical to R9.
#define ACC4(HV, R) do {                                       \
    f32x2 _hb = {(HV), (HV)};                                  \
    p01 = __builtin_elementwise_fma(_hb, (R).xy, p01);         \
    p23 = __builtin_elementwise_fma(_hb, (R).zw, p23);         \
} while (0)

// One RNN step. The DENSE block operates on the PREVIOUS step's h (pha/phc,
// registers saved across the barrier) and is placed right after this step's
// h ds_reads — it executes inside the ~120cy LDS latency window, off the
// barrier-critical path. Tv from LDS T-table, prefetched one full step ahead.
#define RNN_STEP(HSRC, HDST, DENSEF, LOADPAIRF, IDP, TOFF, DOSTORE, OUTP) do {      \
    PINW();                                                                         \
    if (DENSEF) PIND();                                                             \
    int2 idpr_n = idpr;                                                             \
    if (LOADPAIRF) idpr_n = *(const int2*)((IDP) + 2);   /* ids[t+2..t+3], b64 */   \
    float Tv_n = lds_T[(TOFF) + id_next * H_ + jdiag];   /* LDS prefetch t+1 */     \
    const f32x4* hbp = (const f32x4*)((HSRC) + 12 * kk);                            \
    f32x4 ha = hbp[0], hc = hbp[1];                      /* 2x ds_read_b128 */      \
    if (DENSEF) {                                        /* fills h-read latency */ \
        f32x2 d2 = pha.xy * D0.xy;                                                  \
        d2 = __builtin_elementwise_fma(pha.zw, D0.zw, d2);                          \
        d2 = __builtin_elementwise_fma(phc.xy, D1.xy, d2);                          \
        d2 = __builtin_elementwise_fma(phc.zw, D1.zw, d2);                          \
        float d = d2.x + d2.y;                                                      \
        d = dpp_add<RR1>(dpp_add<RR2>(dpp_add<RR4>(dpp_add<RR8>(d))));              \
        if (DOSTORE) (OUTP)[0] = d + db;                 /* vmcnt never drained */  \
    }                                                                               \
    f32x2 p01 = {0.f, 0.f}, p23 = {0.f, 0.f};                                       \
    ACC4(ha.x, R0); ACC4(ha.y, R1); ACC4(ha.z, R2); ACC4(ha.w, R3);                 \
    ACC4(hc.x, R4); ACC4(hc.y, R5); ACC4(hc.z, R6); ACC4(hc.w, R7);                 \
    float p0 = p01.x, p1 = p01.y, p2 = p23.x, p3 = p23.y;                           \
    p0 = dpp_add<QP_2301>(dpp_add<QP_1032>(p0));                                    \
    p1 = dpp_add<QP_2301>(dpp_add<QP_1032>(p1));                                    \
    p2 = dpp_add<QP_2301>(dpp_add<QP_1032>(p2));                                    \
    p3 = dpp_add<QP_2301>(dpp_add<QP_1032>(p3));                                    \
    float s01 = c1 ? p1 : p0;                                                       \
    float s23 = c1 ? p3 : p2;                                                       \
    float r   = c2 ? s23 : s01;                                                     \
    r = dpp_add<RR8>(r);                                                            \
    r = dpp_add<RR4>(r);                                                            \
    float hnew = fast_tanhf(r + Tv);                                                \
    if (wrlane) (HDST)[wrword] = hnew;                   /* b32, 16 lanes/wave */   \
    if (DENSEF) { pha = ha; phc = hc; }                  /* save for next step */   \
    BAR();                                                                          \
    if (LOADPAIRF) { idpr = idpr_n; id_next = idpr_n.x; }                           \
    else           { id_next = idpr.y; }                                            \
    Tv = Tv_n;                                                                      \
} while (0)

__global__ __attribute__((amdgpu_flat_work_group_size(512, 512), amdgpu_waves_per_eu(2, 2)))
void seq2seq_rnn_kernel(const int* __restrict__ enc_ids, const int* __restrict__ dec_ids,
                        const float* __restrict__ embed,
                        const float* __restrict__ enc_Wx, const float* __restrict__ enc_Wh,
                        const float* __restrict__ enc_b,
                        const float* __restrict__ dec_Wx, const float* __restrict__ dec_Wh,
                        const float* __restrict__ dec_b,
                        const float* __restrict__ dense_W, const float* __restrict__ dense_b,
                        float* __restrict__ out) {
    __shared__ __align__(16) float lds_T[2 * V_ * H_];   // xw tables [tbl][v][j]
    __shared__ __align__(16) float lds_emb[V_ * E_];
    __shared__ __align__(16) float lds_h0[192];          // 16 groups of 8, stride 12
    __shared__ __align__(16) float lds_h1[192];
    __shared__ __align__(16) int   lds_ids[2 * S_ + 2];

    const int tid  = threadIdx.x;
    const int b    = blockIdx.x;
    const int lane = tid & 63;
    const int w    = tid >> 6;
    const int jl   = lane >> 4;
    const int kk   = lane & 15;
    const int j0     = (w << 4) + (jl << 2);
    const int jdiag  = j0 + (lane & 3);
    const int wrword = 12 * (jdiag >> 3) + (jdiag & 7);
    const bool wrlane = (kk < 4);
    const bool c1 = (lane & 1) != 0;
    const bool c2 = (lane & 2) != 0;
    const int vd   = (w << 2) | jl;               // dense logit slot (27 of 32 used)

    // ---- stage embed + ids; zero h0 ----
    for (int i = tid; i < V_ * E_; i += 512) lds_emb[i] = embed[i];
    if (tid < 256) ((int2*)lds_ids)[tid] = ((const int2*)(enc_ids + b * S_))[tid];
    else ((int2*)(lds_ids + S_))[tid - 256] = ((const int2*)(dec_ids + b * S_))[tid - 256];
    if (tid < 2) lds_ids[2 * S_ + tid] = 0;
    if (tid < 192) lds_h0[tid] = 0.0f;
    __syncthreads();

    // ---- fast T-build: thread owns fixed j-pair, streams Wx rows as f32x2 ----
    // threads 0-255: encoder table; 256-511: decoder. jd=j-pair, g=v-group.
    {
        const int half2 = tid >> 8;
        const int t8    = tid & 255;
        const int jd    = t8 & 63;
        const int g     = t8 >> 6;
        const float* Wx = half2 ? dec_Wx : enc_Wx;
        const float* bb = half2 ? dec_b : enc_b;
        float* Tt = lds_T + half2 * (V_ * H_);
        f32x2 a0={0,0}, a1={0,0}, a2={0,0}, a3={0,0}, a4={0,0}, a5={0,0}, a6={0,0};
        const bool s6ok = (g + 24) < V_;
        for (int e = 0; e < E_; ++e) {
            f32x2 w2 = *(const f32x2*)(Wx + e * H_ + 2 * jd);
            float e0 = lds_emb[(g +  0) * E_ + e]; f32x2 v0 = {e0, e0};
            float e1 = lds_emb[(g +  4) * E_ + e]; f32x2 v1 = {e1, e1};
            float e2 = lds_emb[(g +  8) * E_ + e]; f32x2 v2 = {e2, e2};
            float e3 = lds_emb[(g + 12) * E_ + e]; f32x2 v3 = {e3, e3};
            float e4 = lds_emb[(g + 16) * E_ + e]; f32x2 v4 = {e4, e4};
            float e5 = lds_emb[(g + 20) * E_ + e]; f32x2 v5 = {e5, e5};
            a0 = __builtin_elementwise_fma(v0, w2, a0);
            a1 = __builtin_elementwise_fma(v1, w2, a1);
            a2 = __builtin_elementwise_fma(v2, w2, a2);
            a3 = __builtin_elementwise_fma(v3, w2, a3);
            a4 = __builtin_elementwise_fma(v4, w2, a4);
            a5 = __builtin_elementwise_fma(v5, w2, a5);
            if (s6ok) {
                float e6 = lds_emb[(g + 24) * E_ + e]; f32x2 v6 = {e6, e6};
                a6 = __builtin_elementwise_fma(v6, w2, a6);
            }
        }
        f32x2 bia = *(const f32x2*)(bb + 2 * jd);
        *(f32x2*)(Tt + (g +  0) * H_ + 2 * jd) = a0 + bia;
        *(f32x2*)(Tt + (g +  4) * H_ + 2 * jd) = a1 + bia;
        *(f32x2*)(Tt + (g +  8) * H_ + 2 * jd) = a2 + bia;
        *(f32x2*)(Tt + (g + 12) * H_ + 2 * jd) = a3 + bia;
        *(f32x2*)(Tt + (g + 16) * H_ + 2 * jd) = a4 + bia;
        *(f32x2*)(Tt + (g + 20) * H_ + 2 * jd) = a5 + bia;
        if (s6ok) *(f32x2*)(Tt + (g + 24) * H_ + 2 * jd) = a6 + bia;
    }

    // ---- recurrent weights in named vector registers: Ri = Wh[(8kk+i)*H + j0..j0+3]
    f32x4 R0, R1, R2, R3, R4, R5, R6, R7;
    {
        const float* wp = enc_Wh + (8 * kk) * H_ + j0;
        R0 = *(const f32x4*)(wp + 0 * H_); R1 = *(const f32x4*)(wp + 1 * H_);
        R2 = *(const f32x4*)(wp + 2 * H_); R3 = *(const f32x4*)(wp + 3 * H_);
        R4 = *(const f32x4*)(wp + 4 * H_); R5 = *(const f32x4*)(wp + 5 * H_);
        R6 = *(const f32x4*)(wp + 6 * H_); R7 = *(const f32x4*)(wp + 7 * H_);
    }

    // ---- dense weights: D{0,1}[i] = dense_W[(8kk+i)*V + vd] ----
    f32x4 D0, D1; float db = 0.0f;
    {
        int vc = (vd < V_) ? vd : 0;
        const float* dp = dense_W + (8 * kk) * V_ + vc;
        D0.x = dp[0 * V_]; D0.y = dp[1 * V_]; D0.z = dp[2 * V_]; D0.w = dp[3 * V_];
        D1.x = dp[4 * V_]; D1.y = dp[5 * V_]; D1.z = dp[6 * V_]; D1.w = dp[7 * V_];
        if (vd < V_) db = dense_b[vd];
    }
    const bool dlane = (kk == 0) && (vd < V_);
    float* outd = out + b * (S_ * V_) + vd;
    __syncthreads();   // T tables + h0 ready

    f32x4 pha = {0.f,0.f,0.f,0.f}, phc = {0.f,0.f,0.f,0.f};   // pending-dense state

    // ================= encoder: 512 steps =================
    {
        int2  idpr = make_int2(0, 0);
        int   id_next = lds_ids[1];
        float Tv      = lds_T[lds_ids[0] * H_ + jdiag];
        for (int t = 0; t < S_; t += 2) {
            RNN_STEP(lds_h0, lds_h1, false, true,  lds_ids + t, 0, false, (float*)out);
            RNN_STEP(lds_h1, lds_h0, false, false, lds_ids + t, 0, false, (float*)out);
        }
    }

    // ---- swap to decoder recurrent weights ----
    {
        const float* wp = dec_Wh + (8 * kk) * H_ + j0;
        R0 = *(const f32x4*)(wp + 0 * H_); R1 = *(const f32x4*)(wp + 1 * H_);
        R2 = *(const f32x4*)(wp + 2 * H_); R3 = *(const f32x4*)(wp + 3 * H_);
        R4 = *(const f32x4*)(wp + 4 * H_); R5 = *(const f32x4*)(wp + 5 * H_);
        R6 = *(const f32x4*)(wp + 6 * H_); R7 = *(const f32x4*)(wp + 7 * H_);
    }

    // ================= decoder: 512 steps; dense pipelined one step behind ====
    // Step t saves hsrc (= dec state after t-1) in regs; step t+1 computes its
    // dense inside the h-read latency window -> out[t-1]. Tail handled below.
    {
        const int* ids_d = lds_ids + S_;
        int2  idpr = make_int2(0, 0);
        int   id_next = ids_d[1];
        float Tv      = lds_T[V_ * H_ + ids_d[0] * H_ + jdiag];
        for (int t = 0; t < S_; t += 2) {
            RNN_STEP(lds_h0, lds_h1, true, true,  ids_d + t, V_ * H_,
                     dlane && (t > 0), outd + (t - 2) * V_);
            RNN_STEP(lds_h1, lds_h0, true, false, ids_d + t, V_ * H_,
                     dlane && (t > 0), outd + (t - 1) * V_);
        }
    }

    // epilogue 1: dense on pending (= state after step 510) -> logits[510]
    {
        f32x2 d2 = pha.xy * D0.xy;
        d2 = __builtin_elementwise_fma(pha.zw, D0.zw, d2);
        d2 = __builtin_elementwise_fma(phc.xy, D1.xy, d2);
        d2 = __builtin_elementwise_fma(phc.zw, D1.zw, d2);
        float d = d2.x + d2.y;
        d = dpp_add<RR1>(dpp_add<RR2>(dpp_add<RR4>(dpp_add<RR8>(d))));
        if (dlane) outd[(S_ - 2) * V_] = d + db;
    }
    // epilogue 2: dense on final state (decoder ended writing lds_h0) -> logits[511]
    {
        const f32x4* hbp = (const f32x4*)(lds_h0 + 12 * kk);
        f32x4 ha = hbp[0], hc = hbp[1];
        f32x2 d2 = ha.xy * D0.xy;
        d2 = __builtin_elementwise_fma(ha.zw, D0.zw, d2);
        d2 = __builtin_elementwise_fma(hc.xy, D1.xy, d2);
        d2 = __builtin_elementwise_fma(hc.zw, D1.zw, d2);
        float d = d2.x + d2.y;
        d = dpp_add<RR1>(dpp_add<RR2>(dpp_add<RR4>(dpp_add<RR8>(d))));
        if (dlane) outd[(S_ - 1) * V_] = d + db;
    }
}

extern "C" void kernel_launch(void* const* d_in, const int* in_sizes, int n_in,
                              void* d_out, int out_size, void* d_ws, size_t ws_size,
                              hipStream_t stream) {
    const int*   enc_ids = (const int*)d_in[0];
    const int*   dec_ids = (const int*)d_in[1];
    const float* embed   = (const float*)d_in[2];
    const float* enc_Wx  = (const float*)d_in[3];
    const float* enc_Wh  = (const float*)d_in[4];
    const float* enc_b   = (const float*)d_in[5];
    const float* dec_Wx  = (const float*)d_in[6];
    const float* dec_Wh  = (const float*)d_in[7];
    const float* dec_b   = (const float*)d_in[8];
    const float* dense_W = (const float*)d_in[9];
    const float* dense_b = (const float*)d_in[10];
    float* out = (float*)d_out;

    hipLaunchKernelGGL(seq2seq_rnn_kernel, dim3(256), dim3(512), 0, stream,
                       enc_ids, dec_ids, embed, enc_Wx, enc_Wh, enc_b,
                       dec_Wx, dec_Wh, dec_b, dense_W, dense_b, out);
}